// Round 1
// baseline (34.823 us; speedup 1.0000x reference)
//
#include <hip/hip_runtime.h>

// SplineLayer: x (65536, 512) f32, coeffs (512, 64) f32 -> out (65536,) f32
// out[b] = sum_f w0*coeffs[f,t0] + w1*coeffs[f,t0+1],
//   t = (x+3)/6*63, t0 = clamp(floor(t),0,62), w1 = t - t0.
//
// Strategy: memory-bound (128 MiB x read). Block(256thr/4waves) owns 64 rows.
// Stage x coalesced -> LDS (pad-129 stride), process transposed: lane=row,
// all lanes on same feature => coeffs row lives 1-float-per-lane, gather is
// two __shfl (ds_bpermute) -- no scattered memory gathers at all.

#define TILE_B 64
#define CHUNK_F 128
#define NCHUNK 4           // 512 / 128
#define LSTRIDE 129        // padded LDS row stride in floats (bank: (lane+f)%32 -> 2-way, free)
#define FPW 32             // features per wave per chunk (128 / 4 waves)

__global__ __launch_bounds__(256, 4)
void spline_kernel(const float* __restrict__ x,
                   const float* __restrict__ coeffs,
                   float* __restrict__ out)
{
    __shared__ float ldsX[TILE_B * LSTRIDE];   // 33,024 B
    __shared__ float ldsR[4 * TILE_B];         // 1 KiB cross-wave partials

    const int t    = threadIdx.x;
    const int lane = t & 63;
    const int w    = t >> 6;
    const long rowBase = (long)blockIdx.x * TILE_B;

    float acc0 = 0.0f, acc1 = 0.0f;

    for (int ch = 0; ch < NCHUNK; ++ch) {
        const int cbase = ch * CHUNK_F;
        __syncthreads();   // previous chunk's readers done before overwrite
        // ---- stage 64 rows x 128 cols, coalesced float4 global loads ----
        #pragma unroll
        for (int s = 0; s < 8; ++s) {
            int i4 = s * 256 + t;          // float4 index within chunk (0..2047)
            int r  = i4 >> 5;              // 32 float4 per row
            int c4 = i4 & 31;
            const float4 v = *reinterpret_cast<const float4*>(
                x + (rowBase + r) * 512 + cbase + c4 * 4);
            float* dst = &ldsX[r * LSTRIDE + c4 * 4];
            dst[0] = v.x; dst[1] = v.y; dst[2] = v.z; dst[3] = v.w;
        }
        __syncthreads();
        // ---- process: lane = row, wave w covers features [w*32, w*32+32) ----
        #pragma unroll 8
        for (int j = 0; j < FPW; ++j) {
            const int fc = w * FPW + j;
            const int f  = cbase + fc;
            // coeffs row f: one float per lane (lane = knot index), coalesced 256B
            const float cr = coeffs[f * 64 + lane];
            const float xv = ldsX[lane * LSTRIDE + fc];
            const float tt  = (xv + 3.0f) * 10.5f;      // (x-XMIN)/(XMAX-XMIN)*(K-1)
            float t0f = floorf(tt);
            t0f = fminf(fmaxf(t0f, 0.0f), 62.0f);       // v_med3
            const int t0 = (int)t0f;
            const float c0 = __shfl(cr, t0, 64);        // gather via ds_bpermute
            const float c1 = __shfl(cr, t0 + 1, 64);
            const float w1 = tt - t0f;
            if (j & 1) acc1 += c0 + w1 * (c1 - c0);
            else       acc0 += c0 + w1 * (c1 - c0);
        }
    }

    // ---- cross-wave reduction: 4 partials per row ----
    ldsR[w * TILE_B + lane] = acc0 + acc1;
    __syncthreads();
    if (t < TILE_B) {
        float r = ldsR[t] + ldsR[TILE_B + t] + ldsR[2 * TILE_B + t] + ldsR[3 * TILE_B + t];
        out[rowBase + t] = r;
    }
}

extern "C" void kernel_launch(void* const* d_in, const int* in_sizes, int n_in,
                              void* d_out, int out_size, void* d_ws, size_t ws_size,
                              hipStream_t stream) {
    const float* x      = (const float*)d_in[0];   // (65536, 512)
    const float* coeffs = (const float*)d_in[1];   // (512, 64)
    float* out = (float*)d_out;                    // (65536,)
    (void)in_sizes; (void)n_in; (void)out_size; (void)d_ws; (void)ws_size;

    dim3 grid(65536 / TILE_B);   // 1024 blocks
    dim3 block(256);
    spline_kernel<<<grid, block, 0, stream>>>(x, coeffs, out);
}